// Round 14
// baseline (124.134 us; speedup 1.0000x reference)
//
#include <hip/hip_runtime.h>
#include <stdint.h>

typedef float f32x4 __attribute__((ext_vector_type(4)));
typedef float f32x2 __attribute__((ext_vector_type(2)));
typedef long lng2 __attribute__((ext_vector_type(2)));

#define B_TOTAL 8192
#define DDIM 256            // k elements; 1 byte each in fp8
#define TILE 128            // tile edge; 4 waves x 32 rows
#define NTILE (B_TOTAL / TILE)             // 64
#define NPAIRS (NTILE * (NTILE + 1) / 2)   // 2080 blocks: tiles J>=I
// sqrt((1/T)/ln2): fold temperature+log2e into the fp8 embeddings (both operands)
#define SCALE_HALF 3.79828546f
#define LN2F 0.6931471805599453f

// ---- prep: fp32->fp8 e4m3, two layouts (A row-perm, B fragment-major), LUT --
// A layout (EbA): row-major rows, within row byte p = g*64 + kw*8 + e for
//   original k = kw*32 + g*8 + e (g = k-group = lane>>4 of consumer).
// B layout (Bf): fragment-major: 16-col tile ct, k-window-pair kw8, lane:
//   byte = ct*4096 + kw8*1024 + lane*16  -> wave load = uniform base + lane*16.
__global__ __launch_bounds__(256) void prep_all(
    const float* __restrict__ E, const int* __restrict__ lab,
    unsigned char* __restrict__ EbA, unsigned char* __restrict__ Bf,
    unsigned int* __restrict__ plab, float* __restrict__ posAll,
    unsigned int* __restrict__ lut) {
  const int t = blockIdx.x * 256 + threadIdx.x;   // 262144 threads, 8 floats each
  const float4* s4 = (const float4*)E + (size_t)t * 2;
  float4 v0 = s4[0], v1 = s4[1];
  unsigned int d0 = (unsigned int)__builtin_amdgcn_cvt_pk_fp8_f32(
      v0.x * SCALE_HALF, v0.y * SCALE_HALF, 0, false);
  d0 = (unsigned int)__builtin_amdgcn_cvt_pk_fp8_f32(
      v0.z * SCALE_HALF, v0.w * SCALE_HALF, (int)d0, true);
  unsigned int d1 = (unsigned int)__builtin_amdgcn_cvt_pk_fp8_f32(
      v1.x * SCALE_HALF, v1.y * SCALE_HALF, 0, false);
  d1 = (unsigned int)__builtin_amdgcn_cvt_pk_fp8_f32(
      v1.z * SCALE_HALF, v1.w * SCALE_HALF, (int)d1, true);
  const unsigned long long v8 =
      (unsigned long long)d0 | ((unsigned long long)d1 << 32);
  const int row = t >> 5, j = t & 31;             // j-th group of 8 consecutive k
  // A layout
  *(unsigned long long*)(EbA + (size_t)row * DDIM + ((j & 3) * 64 + (j >> 2) * 8)) = v8;
  // B fragment-major layout
  const unsigned int boff = (unsigned int)(row >> 4) * 4096u +
                            (unsigned int)(j >> 3) * 1024u +
                            (unsigned int)(j & 3) * 256u +
                            (unsigned int)(row & 15) * 16u +
                            (unsigned int)((j >> 2) & 1) * 8u;
  *(unsigned long long*)(Bf + boff) = v8;
  if (t < B_TOTAL) {
    int4 l = ((const int4*)lab)[t];   // labels arrive as int32
    // positional one-hot: aspect a (value 0..5) occupies bits [6a, 6a+6)
    plab[t] = (1u << ((unsigned)l.x & 31u))
            | (1u << (((unsigned)l.y & 31u) + 6u))
            | (1u << (((unsigned)l.z & 31u) + 12u))
            | (1u << (((unsigned)l.w & 31u) + 18u));
  }
  if (t < 2 * B_TOTAL) posAll[t] = 0.0f;   // posArr+allArr contiguous
  if (t < NTILE * NTILE) {                 // forward-map triangle LUT
    const int I = t >> 6, J = t & 63;
    if (J >= I) {
      const int idx = I * NTILE - (I * (I - 1)) / 2 + (J - I);
      lut[idx] = ((unsigned)I << 8) | (unsigned)J;
    }
  }
}

// ---- fused symmetric tile kernel: barrier-free, scatter both triangles ------
template <int DIAGT>
__device__ __forceinline__ void epi_n(
    const f32x4 (&acc)[2], int n, int colbase, int l15, int l4,
    const unsigned int (&pi)[2][4], const int (&irow)[2][4],
    const unsigned int* __restrict__ plab_col,
    f32x2 (&pos2)[2][2], f32x2 (&all2)[2][2],
    float* __restrict__ posArr, float* __restrict__ allArr) {
  const int j = colbase + n * 16 + l15;
  const unsigned int hj = plab_col[n * 16 + l15];
  float colp = 0.f, cola = 0.f;
#pragma unroll
  for (int m = 0; m < 2; ++m) {
    float e[4];
#pragma unroll
    for (int q = 0; q < 4; ++q) {
      float v = __builtin_amdgcn_exp2f(acc[m][q]);   // acc already scaled
      if (DIAGT) { if (j == irow[m][q]) v = 0.0f; }
      e[q] = v;
    }
    f32x2 p01 = { (pi[m][0] & hj) ? e[0] : 0.0f, (pi[m][1] & hj) ? e[1] : 0.0f };
    f32x2 p23 = { (pi[m][2] & hj) ? e[2] : 0.0f, (pi[m][3] & hj) ? e[3] : 0.0f };
    all2[m][0] += (f32x2){e[0], e[1]};
    all2[m][1] += (f32x2){e[2], e[3]};
    pos2[m][0] += p01;
    pos2[m][1] += p23;
    if (!DIAGT) {   // column sums feed the mirrored (J,I) tile's rows
      cola += (e[0] + e[1]) + (e[2] + e[3]);
      colp += (p01[0] + p01[1]) + (p23[0] + p23[1]);
    }
  }
  if (!DIAGT) {
    colp += __shfl_xor(colp, 16); colp += __shfl_xor(colp, 32);
    cola += __shfl_xor(cola, 16); cola += __shfl_xor(cola, 32);
    if (l4 == 0) {
      atomicAdd(&posArr[j], colp);
      atomicAdd(&allArr[j], cola);
    }
  }
}

template <int DIAGT>
__device__ __forceinline__ void tile_body(
    const unsigned char* __restrict__ Bf, int ctbase,
    const unsigned int* __restrict__ plab_col,
    const long (&afrag)[2][8], const unsigned int (&pi)[2][4],
    const int (&irow)[2][4], int colbase, int l15, int l4, int lane,
    f32x2 (&pos2)[2][2], f32x2 (&all2)[2][2],
    float* __restrict__ posArr, float* __restrict__ allArr) {
  auto loadB = [&](int n, lng2 (&b)[4]) {
    const unsigned char* p = Bf + (size_t)(ctbase + n) * 4096 + (unsigned)lane * 16u;
#pragma unroll
    for (int kw8 = 0; kw8 < 4; ++kw8) b[kw8] = *(const lng2*)(p + kw8 * 1024);
  };
  auto mfmaN = [&](const lng2 (&b)[4], f32x4 (&acc)[2]) {
    acc[0] = (f32x4){0.f, 0.f, 0.f, 0.f};
    acc[1] = (f32x4){0.f, 0.f, 0.f, 0.f};
#pragma unroll
    for (int kw8 = 0; kw8 < 4; ++kw8) {
      acc[0] = __builtin_amdgcn_mfma_f32_16x16x32_fp8_fp8(
          afrag[0][kw8 * 2], b[kw8][0], acc[0], 0, 0, 0);
      acc[1] = __builtin_amdgcn_mfma_f32_16x16x32_fp8_fp8(
          afrag[1][kw8 * 2], b[kw8][0], acc[1], 0, 0, 0);
      acc[0] = __builtin_amdgcn_mfma_f32_16x16x32_fp8_fp8(
          afrag[0][kw8 * 2 + 1], b[kw8][1], acc[0], 0, 0, 0);
      acc[1] = __builtin_amdgcn_mfma_f32_16x16x32_fp8_fp8(
          afrag[1][kw8 * 2 + 1], b[kw8][1], acc[1], 0, 0, 0);
    }
  };
#define EPI(ACC, N) epi_n<DIAGT>(ACC, N, colbase, l15, l4, pi, irow, plab_col, \
                                 pos2, all2, posArr, allArr)
  // rolling 2-buffer / 2-acc pipeline over the 8 column-16-tiles
  lng2 b0[4], b1[4];
  f32x4 accA[2], accB[2];
  loadB(0, b0); loadB(1, b1);
  mfmaN(b0, accA); loadB(2, b0);
  mfmaN(b1, accB); loadB(3, b1);
  EPI(accA, 0);
  mfmaN(b0, accA); loadB(4, b0);
  EPI(accB, 1);
  mfmaN(b1, accB); loadB(5, b1);
  EPI(accA, 2);
  mfmaN(b0, accA); loadB(6, b0);
  EPI(accB, 3);
  mfmaN(b1, accB); loadB(7, b1);
  EPI(accA, 4);
  mfmaN(b0, accA);
  EPI(accB, 5);
  mfmaN(b1, accB);
  EPI(accA, 6);
  EPI(accB, 7);
#undef EPI
}

__global__ __launch_bounds__(256, 2) void main_kernel(
    const unsigned char* __restrict__ EbA, const unsigned char* __restrict__ Bf,
    const unsigned int* __restrict__ plab, const unsigned int* __restrict__ lut,
    float* __restrict__ posArr, float* __restrict__ allArr) {
  __shared__ unsigned int plab_col[TILE];   // 512 B: the only LDS
  const int tid = threadIdx.x;
  const int lane = tid & 63;
  const int wid = tid >> 6;        // 4 waves, each owns 32 rows
  const int l15 = lane & 15;
  const int l4 = lane >> 4;
  const unsigned int pair = lut[blockIdx.x];
  const int I = (int)(pair >> 8), J = (int)(pair & 255u);
  const int rowbase = I * TILE;
  const int colbase = J * TILE;
  const int ctbase = J * 8;

  // A fragments: register-resident, 32 rows x 256 k per wave (32 VGPR in fp8)
  long afrag[2][8];
#pragma unroll
  for (int m = 0; m < 2; ++m) {
    const int row = rowbase + wid * 32 + m * 16 + l15;
    const unsigned char* rp = EbA + (size_t)row * DDIM + l4 * 64;
#pragma unroll
    for (int kw8 = 0; kw8 < 4; ++kw8) {
      lng2 t = *(const lng2*)(rp + kw8 * 16);
      afrag[m][kw8 * 2] = t[0];
      afrag[m][kw8 * 2 + 1] = t[1];
    }
  }

  if (tid < TILE) plab_col[tid] = plab[colbase + tid];

  unsigned int pi[2][4];
  int irow[2][4];
#pragma unroll
  for (int m = 0; m < 2; ++m)
#pragma unroll
    for (int q = 0; q < 4; ++q) {
      const int i = rowbase + wid * 32 + m * 16 + l4 * 4 + q;
      irow[m][q] = i;
      pi[m][q] = plab[i];
    }
  __syncthreads();   // plab_col visible; the only barrier

  f32x2 pos2[2][2] = {};
  f32x2 all2[2][2] = {};

  if (I == J)
    tile_body<1>(Bf, ctbase, plab_col, afrag, pi, irow, colbase,
                 l15, l4, lane, pos2, all2, posArr, allArr);
  else
    tile_body<0>(Bf, ctbase, plab_col, afrag, pi, irow, colbase,
                 l15, l4, lane, pos2, all2, posArr, allArr);

  // row-side: reduce across the 16 lanes sharing rows, one atomic per row
#pragma unroll
  for (int m = 0; m < 2; ++m)
#pragma unroll
    for (int q = 0; q < 4; ++q) {
      float p = pos2[m][q >> 1][q & 1], al = all2[m][q >> 1][q & 1];
      p += __shfl_xor(p, 1); p += __shfl_xor(p, 2);
      p += __shfl_xor(p, 4); p += __shfl_xor(p, 8);
      al += __shfl_xor(al, 1); al += __shfl_xor(al, 2);
      al += __shfl_xor(al, 4); al += __shfl_xor(al, 8);
      if (l15 == 0) {
        atomicAdd(&posArr[irow[m][q]], p);
        atomicAdd(&allArr[irow[m][q]], al);
      }
    }
}

// ---- finalize: row losses + mean (separate launch = free ordering) ----------
__global__ __launch_bounds__(1024) void finalize_kernel(
    const float* __restrict__ posArr, const float* __restrict__ allArr,
    float* __restrict__ out) {
  float ls = 0.f, cnt = 0.f;
#pragma unroll
  for (int k = 0; k < B_TOTAL / 1024; ++k) {
    const int i = threadIdx.x + (k << 10);
    const float p = posArr[i];
    const float a = allArr[i];
    if (p > 0.f) {
      ls += (__builtin_amdgcn_logf(a + 1e-8f) - __builtin_amdgcn_logf(p)) * LN2F;
      cnt += 1.f;
    }
  }
#pragma unroll
  for (int msk = 1; msk < 64; msk <<= 1) {
    ls += __shfl_xor(ls, msk);
    cnt += __shfl_xor(cnt, msk);
  }
  __shared__ float sls[16], scnt[16];
  const int w = threadIdx.x >> 6;
  if ((threadIdx.x & 63) == 0) { sls[w] = ls; scnt[w] = cnt; }
  __syncthreads();
  if (threadIdx.x == 0) {
    float L = 0.f, C = 0.f;
    for (int i = 0; i < 16; ++i) { L += sls[i]; C += scnt[i]; }
    out[0] = (C > 0.f) ? L / fmaxf(C, 1.f) : 0.f;
  }
}

// ---- launch -----------------------------------------------------------------
extern "C" void kernel_launch(void* const* d_in, const int* in_sizes, int n_in,
                              void* d_out, int out_size, void* d_ws, size_t ws_size,
                              hipStream_t stream) {
  const float* E = (const float*)d_in[0];
  const int* lab = (const int*)d_in[1];
  float* out = (float*)d_out;
  char* ws = (char*)d_ws;

  unsigned char* EbA = (unsigned char*)ws;                        // 2 MB
  unsigned char* Bf = (unsigned char*)(ws + 2u * 1024u * 1024u);  // 2 MB
  unsigned int* plab = (unsigned int*)(ws + 4u * 1024u * 1024u);  // 32 KB
  float* posArr = (float*)(ws + 4u * 1024u * 1024u + 32u * 1024u);
  float* allArr = posArr + B_TOTAL;                               // 64 KB both
  unsigned int* lut = (unsigned int*)(allArr + B_TOTAL);          // 8.3 KB

  prep_all<<<1024, 256, 0, stream>>>(E, lab, EbA, Bf, plab, posArr, lut);
  main_kernel<<<NPAIRS, 256, 0, stream>>>(EbA, Bf, plab, lut, posArr, allArr);
  finalize_kernel<<<1, 1024, 0, stream>>>(posArr, allArr, out);
}

// Round 15
// 101.249 us; speedup vs baseline: 1.2260x; 1.2260x over previous
//
#include <hip/hip_runtime.h>
#include <stdint.h>

typedef float f32x4 __attribute__((ext_vector_type(4)));
typedef float f32x2 __attribute__((ext_vector_type(2)));
typedef long lng2 __attribute__((ext_vector_type(2)));

#define B_TOTAL 8192
#define DDIM 256            // k elements; 1 byte each in fp8
#define BM 128              // rows per block (4 waves x 32)
#define BN 64               // cols per iter
#define NSPLIT 32
#define COLS_PER (B_TOTAL / NSPLIT)        // 256
#define ITERS (COLS_PER / BN)              // 4
#define NBLOCKS ((B_TOTAL / BM) * NSPLIT)  // 2048 blocks x 256 thr
// sqrt((1/T)/ln2): fold temperature+log2e into the fp8 embeddings (both operands)
#define SCALE_HALF 3.79828546f
#define LN2F 0.6931471805599453f

// ---- prep: fp32->fp8 e4m3, two layouts (A row-perm, B fragment-major) -------
// A layout (EbA): row-major rows, within row byte p = g*64 + kw*8 + e for
//   original k = kw*32 + g*8 + e (g = k-group = lane>>4 of consumer).
// B layout (Bf): fragment-major: 16-col tile ct, k-window-pair kw8, lane(l15,l4):
//   byte = ct*4096 + kw8*1024 + l4*256 + l15*16 + half*8  (half = kw&1)
//   -> a wave's b128 fragment load is uniform_base + lane*16 (perfect coalesce).
__global__ __launch_bounds__(256) void prep_all(
    const float* __restrict__ E, const int* __restrict__ lab,
    unsigned char* __restrict__ EbA, unsigned char* __restrict__ Bf,
    unsigned int* __restrict__ plab, float* __restrict__ posAll) {
  const int t = blockIdx.x * 256 + threadIdx.x;   // 262144 threads, 8 floats each
  const float4* s4 = (const float4*)E + (size_t)t * 2;
  float4 v0 = s4[0], v1 = s4[1];
  unsigned int d0 = (unsigned int)__builtin_amdgcn_cvt_pk_fp8_f32(
      v0.x * SCALE_HALF, v0.y * SCALE_HALF, 0, false);
  d0 = (unsigned int)__builtin_amdgcn_cvt_pk_fp8_f32(
      v0.z * SCALE_HALF, v0.w * SCALE_HALF, (int)d0, true);
  unsigned int d1 = (unsigned int)__builtin_amdgcn_cvt_pk_fp8_f32(
      v1.x * SCALE_HALF, v1.y * SCALE_HALF, 0, false);
  d1 = (unsigned int)__builtin_amdgcn_cvt_pk_fp8_f32(
      v1.z * SCALE_HALF, v1.w * SCALE_HALF, (int)d1, true);
  const unsigned long long v8 =
      (unsigned long long)d0 | ((unsigned long long)d1 << 32);
  const int row = t >> 5, j = t & 31;             // j-th group of 8 consecutive k
  // A layout
  *(unsigned long long*)(EbA + (size_t)row * DDIM + ((j & 3) * 64 + (j >> 2) * 8)) = v8;
  // B fragment-major layout
  const unsigned int boff = (unsigned int)(row >> 4) * 4096u +
                            (unsigned int)(j >> 3) * 1024u +
                            (unsigned int)(j & 3) * 256u +
                            (unsigned int)(row & 15) * 16u +
                            (unsigned int)((j >> 2) & 1) * 8u;
  *(unsigned long long*)(Bf + boff) = v8;
  if (t < B_TOTAL) {
    int4 l = ((const int4*)lab)[t];   // labels arrive as int32
    // positional one-hot: aspect a (value 0..5) occupies bits [6a, 6a+6)
    plab[t] = (1u << ((unsigned)l.x & 31u))
            | (1u << (((unsigned)l.y & 31u) + 6u))
            | (1u << (((unsigned)l.z & 31u) + 12u))
            | (1u << (((unsigned)l.w & 31u) + 18u));
  }
  if (t < 2 * B_TOTAL) posAll[t] = 0.0f;   // posArr+allArr contiguous
}

// ---- fused sim/exp/mask/rowsum: barrier-free free-running waves -------------
template <int DIAG>
__device__ __forceinline__ void epi_n(
    const f32x4 (&acc)[2], int n, int colbase, int itBN, int l15,
    const unsigned int (&pi)[2][4], const int (&irow)[2][4],
    const unsigned int* __restrict__ plab_all,
    f32x2 (&pos2)[2][2], f32x2 (&all2)[2][2]) {
  const int j = colbase + n * 16 + l15;
  const unsigned int hj = plab_all[itBN + n * 16 + l15];
#pragma unroll
  for (int m = 0; m < 2; ++m) {
    float e[4];
#pragma unroll
    for (int q = 0; q < 4; ++q) {
      float v = __builtin_amdgcn_exp2f(acc[m][q]);   // acc already scaled
      if (DIAG) { if (j == irow[m][q]) v = 0.0f; }
      e[q] = v;
    }
    f32x2 p01 = { (pi[m][0] & hj) ? e[0] : 0.0f, (pi[m][1] & hj) ? e[1] : 0.0f };
    f32x2 p23 = { (pi[m][2] & hj) ? e[2] : 0.0f, (pi[m][3] & hj) ? e[3] : 0.0f };
    all2[m][0] += (f32x2){e[0], e[1]};
    all2[m][1] += (f32x2){e[2], e[3]};
    pos2[m][0] += p01;
    pos2[m][1] += p23;
  }
}

template <int DIAG>
__device__ __forceinline__ void iter_body(
    const unsigned char* __restrict__ Bf, int ctbase,
    const unsigned int* __restrict__ plab_all,
    const long (&afrag)[2][8], const unsigned int (&pi)[2][4],
    const int (&irow)[2][4], int colbase, int itBN, int l15, int lane,
    f32x2 (&pos2)[2][2], f32x2 (&all2)[2][2]) {
  auto loadB = [&](int n, lng2 (&b)[4]) {
    const unsigned char* p = Bf + (size_t)(ctbase + n) * 4096 + (unsigned)lane * 16u;
#pragma unroll
    for (int kw8 = 0; kw8 < 4; ++kw8) b[kw8] = *(const lng2*)(p + kw8 * 1024);
  };
  auto mfmaN = [&](const lng2 (&b)[4], f32x4 (&acc)[2]) {
    acc[0] = (f32x4){0.f, 0.f, 0.f, 0.f};
    acc[1] = (f32x4){0.f, 0.f, 0.f, 0.f};
#pragma unroll
    for (int kw8 = 0; kw8 < 4; ++kw8) {
      acc[0] = __builtin_amdgcn_mfma_f32_16x16x32_fp8_fp8(
          afrag[0][kw8 * 2], b[kw8][0], acc[0], 0, 0, 0);
      acc[1] = __builtin_amdgcn_mfma_f32_16x16x32_fp8_fp8(
          afrag[1][kw8 * 2], b[kw8][0], acc[1], 0, 0, 0);
      acc[0] = __builtin_amdgcn_mfma_f32_16x16x32_fp8_fp8(
          afrag[0][kw8 * 2 + 1], b[kw8][1], acc[0], 0, 0, 0);
      acc[1] = __builtin_amdgcn_mfma_f32_16x16x32_fp8_fp8(
          afrag[1][kw8 * 2 + 1], b[kw8][1], acc[1], 0, 0, 0);
    }
  };
  // software pipeline: loads 2 tiles ahead; epilogues fill MFMA/load latency
  lng2 b0[4], b1[4], b2_[4], b3[4];
  f32x4 accA[2], accB[2];
  loadB(0, b0); loadB(1, b1);
  mfmaN(b0, accA); loadB(2, b2_);
  mfmaN(b1, accB);
  epi_n<DIAG>(accA, 0, colbase, itBN, l15, pi, irow, plab_all, pos2, all2);
  mfmaN(b2_, accA); loadB(3, b3);
  epi_n<DIAG>(accB, 1, colbase, itBN, l15, pi, irow, plab_all, pos2, all2);
  mfmaN(b3, accB);
  epi_n<DIAG>(accA, 2, colbase, itBN, l15, pi, irow, plab_all, pos2, all2);
  epi_n<DIAG>(accB, 3, colbase, itBN, l15, pi, irow, plab_all, pos2, all2);
}

__global__ __launch_bounds__(256, 2) void main_kernel(
    const unsigned char* __restrict__ EbA, const unsigned char* __restrict__ Bf,
    const unsigned int* __restrict__ plab,
    float* __restrict__ posArr, float* __restrict__ allArr) {
  __shared__ unsigned int plab_all[COLS_PER];   // 1 KB: the only LDS
  const int tid = threadIdx.x;
  const int lane = tid & 63;
  const int wid = tid >> 6;        // 4 waves, each owns 32 rows
  const int l15 = lane & 15;
  const int l4 = lane >> 4;
  const int rb = (int)blockIdx.x & 63;   // 64 row-blocks of 128
  const int cs = (int)blockIdx.x >> 6;   // 32 column panels of 256
  const int rowbase = rb * BM;
  const int colstart = cs * COLS_PER;

  // A fragments: register-resident, 32 rows x 256 k per wave (32 VGPR in fp8)
  long afrag[2][8];
#pragma unroll
  for (int m = 0; m < 2; ++m) {
    const int row = rowbase + wid * 32 + m * 16 + l15;
    const unsigned char* rp = EbA + (size_t)row * DDIM + l4 * 64;
#pragma unroll
    for (int kw8 = 0; kw8 < 4; ++kw8) {
      lng2 t = *(const lng2*)(rp + kw8 * 16);
      afrag[m][kw8 * 2] = t[0];
      afrag[m][kw8 * 2 + 1] = t[1];
    }
  }

  // panel labels -> LDS once; the ONLY barrier in the kernel
  plab_all[tid] = plab[colstart + tid];

  unsigned int pi[2][4];
  int irow[2][4];
#pragma unroll
  for (int m = 0; m < 2; ++m)
#pragma unroll
    for (int q = 0; q < 4; ++q) {
      const int i = rowbase + wid * 32 + m * 16 + l4 * 4 + q;
      irow[m][q] = i;
      pi[m][q] = plab[i];
    }
  __syncthreads();

  f32x2 pos2[2][2] = {};
  f32x2 all2[2][2] = {};

  for (int it = 0; it < ITERS; ++it) {
    const int colbase = colstart + it * BN;
    const int ctbase = colbase >> 4;
    const bool hasDiag = (colbase < rowbase + BM) && (rowbase < colbase + BN);
    if (hasDiag)
      iter_body<1>(Bf, ctbase, plab_all, afrag, pi, irow,
                   colbase, it * BN, l15, lane, pos2, all2);
    else
      iter_body<0>(Bf, ctbase, plab_all, afrag, pi, irow,
                   colbase, it * BN, l15, lane, pos2, all2);
  }

  // reduce across the 16 lanes sharing the same rows, then one atomic per row
#pragma unroll
  for (int m = 0; m < 2; ++m)
#pragma unroll
    for (int q = 0; q < 4; ++q) {
      float p = pos2[m][q >> 1][q & 1], al = all2[m][q >> 1][q & 1];
      p += __shfl_xor(p, 1); p += __shfl_xor(p, 2);
      p += __shfl_xor(p, 4); p += __shfl_xor(p, 8);
      al += __shfl_xor(al, 1); al += __shfl_xor(al, 2);
      al += __shfl_xor(al, 4); al += __shfl_xor(al, 8);
      if (l15 == 0) {
        atomicAdd(&posArr[irow[m][q]], p);
        atomicAdd(&allArr[irow[m][q]], al);
      }
    }
}

// ---- finalize: row losses + mean (separate launch = free ordering) ----------
__global__ __launch_bounds__(1024) void finalize_kernel(
    const float* __restrict__ posArr, const float* __restrict__ allArr,
    float* __restrict__ out) {
  float ls = 0.f, cnt = 0.f;
#pragma unroll
  for (int k = 0; k < B_TOTAL / 1024; ++k) {
    const int i = threadIdx.x + (k << 10);
    const float p = posArr[i];
    const float a = allArr[i];
    if (p > 0.f) {
      ls += (__builtin_amdgcn_logf(a + 1e-8f) - __builtin_amdgcn_logf(p)) * LN2F;
      cnt += 1.f;
    }
  }
#pragma unroll
  for (int msk = 1; msk < 64; msk <<= 1) {
    ls += __shfl_xor(ls, msk);
    cnt += __shfl_xor(cnt, msk);
  }
  __shared__ float sls[16], scnt[16];
  const int w = threadIdx.x >> 6;
  if ((threadIdx.x & 63) == 0) { sls[w] = ls; scnt[w] = cnt; }
  __syncthreads();
  if (threadIdx.x == 0) {
    float L = 0.f, C = 0.f;
    for (int i = 0; i < 16; ++i) { L += sls[i]; C += scnt[i]; }
    out[0] = (C > 0.f) ? L / fmaxf(C, 1.f) : 0.f;
  }
}

// ---- launch -----------------------------------------------------------------
extern "C" void kernel_launch(void* const* d_in, const int* in_sizes, int n_in,
                              void* d_out, int out_size, void* d_ws, size_t ws_size,
                              hipStream_t stream) {
  const float* E = (const float*)d_in[0];
  const int* lab = (const int*)d_in[1];
  float* out = (float*)d_out;
  char* ws = (char*)d_ws;

  unsigned char* EbA = (unsigned char*)ws;                        // 2 MB
  unsigned char* Bf = (unsigned char*)(ws + 2u * 1024u * 1024u);  // 2 MB
  unsigned int* plab = (unsigned int*)(ws + 4u * 1024u * 1024u);  // 32 KB
  float* posArr = (float*)(ws + 4u * 1024u * 1024u + 32u * 1024u);
  float* allArr = posArr + B_TOTAL;

  prep_all<<<1024, 256, 0, stream>>>(E, lab, EbA, Bf, plab, posArr);
  main_kernel<<<NBLOCKS, 256, 0, stream>>>(EbA, Bf, plab, posArr, allArr);
  finalize_kernel<<<1, 1024, 0, stream>>>(posArr, allArr, out);
}